// Round 1
// baseline (1053.613 us; speedup 1.0000x reference)
//
#include <hip/hip_runtime.h>

#define DEVFN __device__ __forceinline__

typedef _Float16 f16x8 __attribute__((ext_vector_type(8)));
typedef float f32x4 __attribute__((ext_vector_type(4)));

static constexpr int T   = 8192;   // tokens (B*S)
static constexpr int D   = 1024;
static constexpr int E   = 8;
static constexpr int DFF = 4096;
static constexpr int MAXRT = (2*T)/128 + E;   // 136 max row tiles (grouped)

DEVFN unsigned short f2h_bits(float v){
  _Float16 h = (_Float16)v;           // RNE
  return __builtin_bit_cast(unsigned short, h);
}

DEVFN void gload_lds16(const void* g, void* l){
  __builtin_amdgcn_global_load_lds((const __attribute__((address_space(1))) void*)g,
                                   (__attribute__((address_space(3))) void*)l, 16, 0, 0);
}

// ---------------- cast fp32 -> fp16 (bits in ushort) ----------------
__global__ __launch_bounds__(256) void cast_f16_kernel(const float* __restrict__ in,
                                                       unsigned short* __restrict__ out, int n4){
  int i = blockIdx.x*256 + threadIdx.x;
  if (i >= n4) return;
  float4 v = ((const float4*)in)[i];
  ushort4 o;
  o.x = f2h_bits(v.x); o.y = f2h_bits(v.y); o.z = f2h_bits(v.z); o.w = f2h_bits(v.w);
  ((ushort4*)out)[i] = o;
}

// ---------------- router: fp32 logits, softmax-top2, counts ----------------
__global__ __launch_bounds__(256) void router_kernel(const float* __restrict__ x,
    const float* __restrict__ rw, int* __restrict__ tok_e, float* __restrict__ tok_w,
    int* __restrict__ counts){
  const int lane = threadIdx.x & 63;
  const int t = blockIdx.x*4 + (threadIdx.x >> 6);
  const float4* xp = (const float4*)(x + (size_t)t*D);
  float acc[E];
#pragma unroll
  for (int e=0;e<E;e++) acc[e]=0.f;
#pragma unroll
  for (int i=0;i<4;i++){
    float4 xv = xp[lane + (i<<6)];
#pragma unroll
    for (int e=0;e<E;e++){
      float4 wv = ((const float4*)(rw + e*D))[lane + (i<<6)];
      acc[e] = fmaf(xv.x,wv.x, fmaf(xv.y,wv.y, fmaf(xv.z,wv.z, fmaf(xv.w,wv.w, acc[e]))));
    }
  }
#pragma unroll
  for (int e=0;e<E;e++){
#pragma unroll
    for (int off=32; off>0; off>>=1) acc[e] += __shfl_xor(acc[e], off);
  }
  if (lane==0){
    float l0=-1e30f, l1=-1e30f; int e0=0, e1=0;
#pragma unroll
    for (int e=0;e<E;e++){
      float v = acc[e];
      if (v > l0){ l1=l0; e1=e0; l0=v; e0=e; }
      else if (v > l1){ l1=v; e1=e; }
    }
    // topk weights: p0/(p0+p1) = 1/(1+exp(l1-l0)); softmax denom cancels
    float r   = expf(l1 - l0);
    float inv = 1.f/(1.f + r);
    tok_e[2*t]   = e0; tok_e[2*t+1] = e1;
    tok_w[2*t]   = inv; tok_w[2*t+1] = r*inv;
    atomicAdd(&counts[e0], 1);
    atomicAdd(&counts[e1], 1);
  }
}

// ---------------- scan: offsets + row-tile map ----------------
__global__ void scan_kernel(const int* __restrict__ counts, int* __restrict__ offs,
                            int* __restrict__ tile_e, int* __restrict__ tile_r0,
                            int* __restrict__ nrt){
  if (blockIdx.x==0 && threadIdx.x==0){
    int off=0, nt=0;
    for (int e=0;e<E;e++){
      offs[e]=off;
      int c = counts[e];
      int tiles = (c+127)>>7;
      for (int i=0;i<tiles;i++){ tile_e[nt]=e; tile_r0[nt]=off + (i<<7); nt++; }
      off += c;
    }
    offs[E]=off;
    *nrt = nt;
  }
}

// ---------------- scatter: grouped row -> (token, weight) ----------------
__global__ __launch_bounds__(256) void scatter_kernel(const int* __restrict__ tok_e,
    const float* __restrict__ tok_w, const int* __restrict__ offs,
    int* __restrict__ fill, int* __restrict__ row_tok, float* __restrict__ row_w){
  int idx = blockIdx.x*256 + threadIdx.x;   // [0, 2T)
  int e = tok_e[idx];
  int pos = offs[e] + atomicAdd(&fill[e], 1);
  row_tok[pos] = idx >> 1;
  row_w[pos]   = tok_w[idx];
}

// ---------------- GEMM C = A * B^T, A [M x K] f16, B [N x K] f16 ----------------
// MODE 0: expert fc   (gather x rows via row_tok) -> h = relu(acc)^2, f16
// MODE 1: expert proj (h contiguous)              -> atomicAdd(out[token], w*acc)
// MODE 2: shared fc   (x direct)                  -> h = relu(acc)^2, f16
// MODE 3: shared proj (h direct)                  -> out[token] = acc (plain store)
template<int MODE>
__global__ __launch_bounds__(256) void gemm_kernel(
    const unsigned short* __restrict__ A, const unsigned short* __restrict__ B,
    unsigned short* __restrict__ Hout, float* __restrict__ Out,
    int K, int N,
    const int* __restrict__ tile_e, const int* __restrict__ tile_r0,
    const int* __restrict__ offs, const int* __restrict__ nrt,
    const int* __restrict__ row_tok, const float* __restrict__ row_w)
{
  constexpr bool EXPERT = (MODE==0 || MODE==1);
  constexpr bool S1     = (MODE==0 || MODE==2);

  const int ct = blockIdx.x;
  const int rt = blockIdx.y;
  int row0, row_end;
  const unsigned short* Bp = B;
  if constexpr (EXPERT){
    if (rt >= *nrt) return;
    int e = tile_e[rt];
    row0 = tile_r0[rt];
    row_end = offs[e+1];
    Bp = B + (size_t)e * (size_t)N * (size_t)K;
  } else {
    row0 = rt << 7;
    row_end = row0 + 128;
  }

  __shared__ unsigned short As[128*32];
  __shared__ unsigned short Bs[128*32];

  const int tid  = threadIdx.x;
  const int lane = tid & 63;
  const int wave = tid >> 6;

  // staging: slot s = tid + 256c; 16B per slot; XOR-swizzled k-slot so
  // ds_read_b128 fragment reads are bank-conflict-free (2-way = free).
  const unsigned short* a_src[2];
  const unsigned short* b_src[2];
  unsigned short* a_dst[2];
  unsigned short* b_dst[2];
#pragma unroll
  for (int c=0;c<2;c++){
    int s = tid + (c<<8);
    int r = s >> 2;
    int ksl = (s & 3) ^ ((r >> 1) & 3);
    int ar;
    if constexpr (EXPERT){
      int rr = row0 + r;
      int rmax = row_end - 1;
      if (rr > rmax) rr = rmax;          // clamp padded tile rows (results discarded)
      ar = (MODE==0) ? row_tok[rr] : rr; // MODE0 gathers x rows by token
    } else {
      ar = row0 + r;
    }
    a_src[c] = A  + (size_t)ar*K + ksl*8;
    b_src[c] = Bp + (size_t)((ct<<7) + r)*K + ksl*8;
    a_dst[c] = As + ((c<<8) + (wave<<6))*8;   // linear LDS dest (wave-uniform base)
    b_dst[c] = Bs + ((c<<8) + (wave<<6))*8;
  }

  const int wm = wave >> 1, wn = wave & 1;
  const int csl = lane >> 4;
  int aoff[4], boff[4];
#pragma unroll
  for (int m=0;m<4;m++){
    int r = (wm<<6) + (m<<4) + (lane&15);
    aoff[m] = r*32 + ((csl ^ ((r>>1)&3))<<3);
    r = (wn<<6) + (m<<4) + (lane&15);
    boff[m] = r*32 + ((csl ^ ((r>>1)&3))<<3);
  }

  f32x4 acc[4][4] = {};

  const int nk = K >> 5;
  for (int kt=0; kt<nk; ++kt){
#pragma unroll
    for (int c=0;c<2;c++){
      gload_lds16(a_src[c], a_dst[c]);
      gload_lds16(b_src[c], b_dst[c]);
      a_src[c] += 32;
      b_src[c] += 32;
    }
    __syncthreads();
    f16x8 af[4], bfv[4];
#pragma unroll
    for (int m=0;m<4;m++) af[m] = *(const f16x8*)(As + aoff[m]);
#pragma unroll
    for (int n=0;n<4;n++) bfv[n] = *(const f16x8*)(Bs + boff[n]);
#pragma unroll
    for (int m=0;m<4;m++)
#pragma unroll
      for (int n=0;n<4;n++)
        acc[m][n] = __builtin_amdgcn_mfma_f32_16x16x32_f16(af[m], bfv[n], acc[m][n], 0, 0, 0);
    __syncthreads();
  }

  // epilogue: C row = (lane>>4)*4 + q, col = lane&15 (m89-verified layout)
  const int lcol = lane & 15;
  const int lrow = (lane >> 4) << 2;
#pragma unroll
  for (int m=0;m<4;m++){
#pragma unroll
    for (int q=0;q<4;q++){
      const int grow = row0 + (wm<<6) + (m<<4) + lrow + q;
      if constexpr (EXPERT){ if (grow >= row_end) continue; }
      int orow = grow; float w = 0.f;
      if constexpr (MODE==1){ orow = row_tok[grow]; w = row_w[grow]; }
#pragma unroll
      for (int n=0;n<4;n++){
        const int col = (ct<<7) + (wn<<6) + (n<<4) + lcol;
        float v = acc[m][n][q];
        if constexpr (S1){
          v = (v > 0.f) ? v*v : 0.f;      // relu(x)^2
          Hout[(size_t)grow*N + col] = f2h_bits(v);
        } else if constexpr (MODE==1){
          atomicAdd(Out + (size_t)orow*N + col, w*v);
        } else {
          Out[(size_t)grow*N + col] = v;  // shared expert: plain store (re-inits out)
        }
      }
    }
  }
}

// ---------------- host launcher ----------------
extern "C" void kernel_launch(void* const* d_in, const int* in_sizes, int n_in,
                              void* d_out, int out_size, void* d_ws, size_t ws_size,
                              hipStream_t stream){
  const float* x     = (const float*)d_in[0];
  const float* rw    = (const float*)d_in[1];
  const float* wfc   = (const float*)d_in[2];
  const float* wproj = (const float*)d_in[3];
  const float* sfc   = (const float*)d_in[4];
  const float* sproj = (const float*)d_in[5];
  float* out = (float*)d_out;

  char* ws = (char*)d_ws;
  size_t off = 0;
  auto alloc = [&](size_t bytes)->void*{
    void* p = ws + off; off += (bytes + 255) & ~(size_t)255; return p;
  };
  unsigned short* xb   = (unsigned short*)alloc((size_t)T*D*2);
  unsigned short* wfcb = (unsigned short*)alloc((size_t)E*DFF*D*2);
  unsigned short* wpb  = (unsigned short*)alloc((size_t)E*D*DFF*2);
  unsigned short* sfcb = (unsigned short*)alloc((size_t)DFF*D*2);
  unsigned short* spb  = (unsigned short*)alloc((size_t)D*DFF*2);
  unsigned short* h    = (unsigned short*)alloc((size_t)2*T*DFF*2);
  int*   tok_e   = (int*)  alloc((size_t)T*2*4);
  float* tok_w   = (float*)alloc((size_t)T*2*4);
  int*   row_tok = (int*)  alloc((size_t)2*T*4);
  float* row_w   = (float*)alloc((size_t)2*T*4);
  int* counts  = (int*)alloc(E*4);
  int* fill    = (int*)alloc(E*4);
  int* offs    = (int*)alloc((E+1)*4);
  int* nrt     = (int*)alloc(4);
  int* tile_e  = (int*)alloc(MAXRT*4);
  int* tile_r0 = (int*)alloc(MAXRT*4);
  if (off > ws_size) return;   // workspace too small -> visible zero-output failure

  hipMemsetAsync(counts, 0, E*4, stream);
  hipMemsetAsync(fill,   0, E*4, stream);

  // casts fp32 -> fp16
  cast_f16_kernel<<<(T*D/4)/256,       256, 0, stream>>>(x,     xb,   T*D/4);
  cast_f16_kernel<<<(E*DFF*D/4)/256,   256, 0, stream>>>(wfc,   wfcb, E*DFF*D/4);
  cast_f16_kernel<<<(E*D*DFF/4)/256,   256, 0, stream>>>(wproj, wpb,  E*D*DFF/4);
  cast_f16_kernel<<<(DFF*D/4)/256,     256, 0, stream>>>(sfc,   sfcb, DFF*D/4);
  cast_f16_kernel<<<(D*DFF/4)/256,     256, 0, stream>>>(sproj, spb,  D*DFF/4);

  // routing
  router_kernel <<<T/4, 256, 0, stream>>>(x, rw, tok_e, tok_w, counts);
  scan_kernel   <<<1,   64,  0, stream>>>(counts, offs, tile_e, tile_r0, nrt);
  scatter_kernel<<<(2*T)/256, 256, 0, stream>>>(tok_e, tok_w, offs, fill, row_tok, row_w);

  // shared expert (plain store initializes out)
  gemm_kernel<2><<<dim3(DFF/128, T/128), 256, 0, stream>>>(
      xb, sfcb, h, nullptr, D, DFF, nullptr, nullptr, nullptr, nullptr, nullptr, nullptr);
  gemm_kernel<3><<<dim3(D/128, T/128), 256, 0, stream>>>(
      h, spb, nullptr, out, DFF, D, nullptr, nullptr, nullptr, nullptr, nullptr, nullptr);

  // routed experts (grouped rows; atomic accumulate on top of shared)
  gemm_kernel<0><<<dim3(DFF/128, MAXRT), 256, 0, stream>>>(
      xb, wfcb, h, nullptr, D, DFF, tile_e, tile_r0, offs, nrt, row_tok, row_w);
  gemm_kernel<1><<<dim3(D/128, MAXRT), 256, 0, stream>>>(
      h, wpb, nullptr, out, DFF, D, tile_e, tile_r0, offs, nrt, row_tok, row_w);
}

// Round 2
// 1053.026 us; speedup vs baseline: 1.0006x; 1.0006x over previous
//
#include <hip/hip_runtime.h>

#define DEVFN __device__ __forceinline__

typedef _Float16 f16x8 __attribute__((ext_vector_type(8)));
typedef float f32x4 __attribute__((ext_vector_type(4)));

static constexpr int T   = 8192;   // tokens (B*S)
static constexpr int D   = 1024;
static constexpr int E   = 8;
static constexpr int DFF = 4096;
static constexpr int MAXRT = (2*T)/128 + E;   // 136 max row tiles (grouped)

DEVFN unsigned short f2h_bits(float v){
  _Float16 h = (_Float16)v;           // RNE
  return __builtin_bit_cast(unsigned short, h);
}

DEVFN void gload_lds16(const void* g, void* l){
  __builtin_amdgcn_global_load_lds((const __attribute__((address_space(1))) void*)g,
                                   (__attribute__((address_space(3))) void*)l, 16, 0, 0);
}

// ---------------- cast fp32 -> fp16 (bits in ushort) ----------------
__global__ __launch_bounds__(256) void cast_f16_kernel(const float* __restrict__ in,
                                                       unsigned short* __restrict__ out, int n4){
  int i = blockIdx.x*256 + threadIdx.x;
  if (i >= n4) return;
  float4 v = ((const float4*)in)[i];
  ushort4 o;
  o.x = f2h_bits(v.x); o.y = f2h_bits(v.y); o.z = f2h_bits(v.z); o.w = f2h_bits(v.w);
  ((ushort4*)out)[i] = o;
}

// ---------------- router: fp32 logits, softmax-top2, counts ----------------
__global__ __launch_bounds__(256) void router_kernel(const float* __restrict__ x,
    const float* __restrict__ rw, int* __restrict__ tok_e, float* __restrict__ tok_w,
    int* __restrict__ counts){
  const int lane = threadIdx.x & 63;
  const int t = blockIdx.x*4 + (threadIdx.x >> 6);
  const float4* xp = (const float4*)(x + (size_t)t*D);
  float acc[E];
#pragma unroll
  for (int e=0;e<E;e++) acc[e]=0.f;
#pragma unroll
  for (int i=0;i<4;i++){
    float4 xv = xp[lane + (i<<6)];
#pragma unroll
    for (int e=0;e<E;e++){
      float4 wv = ((const float4*)(rw + e*D))[lane + (i<<6)];
      acc[e] = fmaf(xv.x,wv.x, fmaf(xv.y,wv.y, fmaf(xv.z,wv.z, fmaf(xv.w,wv.w, acc[e]))));
    }
  }
#pragma unroll
  for (int e=0;e<E;e++){
#pragma unroll
    for (int off=32; off>0; off>>=1) acc[e] += __shfl_xor(acc[e], off);
  }
  if (lane==0){
    float l0=-1e30f, l1=-1e30f; int e0=0, e1=0;
#pragma unroll
    for (int e=0;e<E;e++){
      float v = acc[e];
      if (v > l0){ l1=l0; e1=e0; l0=v; e0=e; }
      else if (v > l1){ l1=v; e1=e; }
    }
    // topk weights: p0/(p0+p1) = 1/(1+exp(l1-l0)); softmax denom cancels
    float r   = expf(l1 - l0);
    float inv = 1.f/(1.f + r);
    tok_e[2*t]   = e0; tok_e[2*t+1] = e1;
    tok_w[2*t]   = inv; tok_w[2*t+1] = r*inv;
    atomicAdd(&counts[e0], 1);
    atomicAdd(&counts[e1], 1);
  }
}

// ---------------- scan: offsets + row-tile map ----------------
__global__ void scan_kernel(const int* __restrict__ counts, int* __restrict__ offs,
                            int* __restrict__ tile_e, int* __restrict__ tile_r0,
                            int* __restrict__ nrt){
  if (blockIdx.x==0 && threadIdx.x==0){
    int off=0, nt=0;
    for (int e=0;e<E;e++){
      offs[e]=off;
      int c = counts[e];
      int tiles = (c+127)>>7;
      for (int i=0;i<tiles;i++){ tile_e[nt]=e; tile_r0[nt]=off + (i<<7); nt++; }
      off += c;
    }
    offs[E]=off;
    *nrt = nt;
  }
}

// ---------------- scatter: grouped row -> (token, weight) ----------------
__global__ __launch_bounds__(256) void scatter_kernel(const int* __restrict__ tok_e,
    const float* __restrict__ tok_w, const int* __restrict__ offs,
    int* __restrict__ fill, int* __restrict__ row_tok, float* __restrict__ row_w){
  int idx = blockIdx.x*256 + threadIdx.x;   // [0, 2T)
  int e = tok_e[idx];
  int pos = offs[e] + atomicAdd(&fill[e], 1);
  row_tok[pos] = idx >> 1;
  row_w[pos]   = tok_w[idx];
}

// ---------------- GEMM C = A * B^T, A [M x K] f16, B [N x K] f16 ----------------
// MODE 0: expert fc   (gather x rows via row_tok) -> h = relu(acc)^2, f16
// MODE 1: expert proj (h contiguous)              -> atomicAdd(out[token], w*acc)
// MODE 2: shared fc   (x direct)                  -> h = relu(acc)^2, f16
// MODE 3: shared proj (h direct)                  -> out[token] = acc (plain store)
template<int MODE>
__global__ __launch_bounds__(256) void gemm_kernel(
    const unsigned short* __restrict__ A, const unsigned short* __restrict__ B,
    unsigned short* __restrict__ Hout, float* __restrict__ Out,
    int K, int N,
    const int* __restrict__ tile_e, const int* __restrict__ tile_r0,
    const int* __restrict__ offs, const int* __restrict__ nrt,
    const int* __restrict__ row_tok, const float* __restrict__ row_w)
{
  constexpr bool EXPERT = (MODE==0 || MODE==1);
  constexpr bool S1     = (MODE==0 || MODE==2);

  const int ct = blockIdx.x;
  const int rt = blockIdx.y;
  int row0, row_end;
  const unsigned short* Bp = B;
  if constexpr (EXPERT){
    if (rt >= *nrt) return;
    int e = tile_e[rt];
    row0 = tile_r0[rt];
    row_end = offs[e+1];
    Bp = B + (size_t)e * (size_t)N * (size_t)K;
  } else {
    row0 = rt << 7;
    row_end = row0 + 128;
  }

  __shared__ unsigned short As[128*32];
  __shared__ unsigned short Bs[128*32];

  const int tid  = threadIdx.x;
  const int lane = tid & 63;
  const int wave = tid >> 6;

  // staging: slot s = tid + 256c; 16B per slot; XOR-swizzled k-slot so
  // ds_read_b128 fragment reads are bank-conflict-free (2-way = free).
  const unsigned short* a_src[2];
  const unsigned short* b_src[2];
  unsigned short* a_dst[2];
  unsigned short* b_dst[2];
#pragma unroll
  for (int c=0;c<2;c++){
    int s = tid + (c<<8);
    int r = s >> 2;
    int ksl = (s & 3) ^ ((r >> 1) & 3);
    int ar;
    if constexpr (EXPERT){
      int rr = row0 + r;
      int rmax = row_end - 1;
      if (rr > rmax) rr = rmax;          // clamp padded tile rows (results discarded)
      ar = (MODE==0) ? row_tok[rr] : rr; // MODE0 gathers x rows by token
    } else {
      ar = row0 + r;
    }
    a_src[c] = A  + (size_t)ar*K + ksl*8;
    b_src[c] = Bp + (size_t)((ct<<7) + r)*K + ksl*8;
    a_dst[c] = As + ((c<<8) + (wave<<6))*8;   // linear LDS dest (wave-uniform base)
    b_dst[c] = Bs + ((c<<8) + (wave<<6))*8;
  }

  const int wm = wave >> 1, wn = wave & 1;
  const int csl = lane >> 4;
  int aoff[4], boff[4];
#pragma unroll
  for (int m=0;m<4;m++){
    int r = (wm<<6) + (m<<4) + (lane&15);
    aoff[m] = r*32 + ((csl ^ ((r>>1)&3))<<3);
    r = (wn<<6) + (m<<4) + (lane&15);
    boff[m] = r*32 + ((csl ^ ((r>>1)&3))<<3);
  }

  f32x4 acc[4][4] = {};

  const int nk = K >> 5;
  for (int kt=0; kt<nk; ++kt){
#pragma unroll
    for (int c=0;c<2;c++){
      gload_lds16(a_src[c], a_dst[c]);
      gload_lds16(b_src[c], b_dst[c]);
      a_src[c] += 32;
      b_src[c] += 32;
    }
    __syncthreads();
    f16x8 af[4], bfv[4];
#pragma unroll
    for (int m=0;m<4;m++) af[m] = *(const f16x8*)(As + aoff[m]);
#pragma unroll
    for (int n=0;n<4;n++) bfv[n] = *(const f16x8*)(Bs + boff[n]);
#pragma unroll
    for (int m=0;m<4;m++)
#pragma unroll
      for (int n=0;n<4;n++)
        acc[m][n] = __builtin_amdgcn_mfma_f32_16x16x32_f16(af[m], bfv[n], acc[m][n], 0, 0, 0);
    __syncthreads();
  }

  // epilogue: C row = (lane>>4)*4 + q, col = lane&15 (m89-verified layout)
  const int lcol = lane & 15;
  const int lrow = (lane >> 4) << 2;
#pragma unroll
  for (int m=0;m<4;m++){
#pragma unroll
    for (int q=0;q<4;q++){
      const int grow = row0 + (wm<<6) + (m<<4) + lrow + q;
      if constexpr (EXPERT){ if (grow >= row_end) continue; }
      int orow = grow; float w = 0.f;
      if constexpr (MODE==1){ orow = row_tok[grow]; w = row_w[grow]; }
#pragma unroll
      for (int n=0;n<4;n++){
        const int col = (ct<<7) + (wn<<6) + (n<<4) + lcol;
        float v = acc[m][n][q];
        if constexpr (S1){
          v = (v > 0.f) ? v*v : 0.f;      // relu(x)^2
          Hout[(size_t)grow*N + col] = f2h_bits(v);
        } else if constexpr (MODE==1){
          atomicAdd(Out + (size_t)orow*N + col, w*v);
        } else {
          Out[(size_t)grow*N + col] = v;  // shared expert: plain store (re-inits out)
        }
      }
    }
  }
}

// ---------------- host launcher ----------------
extern "C" void kernel_launch(void* const* d_in, const int* in_sizes, int n_in,
                              void* d_out, int out_size, void* d_ws, size_t ws_size,
                              hipStream_t stream){
  const float* x     = (const float*)d_in[0];
  const float* rw    = (const float*)d_in[1];
  const float* wfc   = (const float*)d_in[2];
  const float* wproj = (const float*)d_in[3];
  const float* sfc   = (const float*)d_in[4];
  const float* sproj = (const float*)d_in[5];
  float* out = (float*)d_out;

  char* ws = (char*)d_ws;
  size_t off = 0;
  auto alloc = [&](size_t bytes)->void*{
    void* p = ws + off; off += (bytes + 255) & ~(size_t)255; return p;
  };
  unsigned short* xb   = (unsigned short*)alloc((size_t)T*D*2);
  unsigned short* wfcb = (unsigned short*)alloc((size_t)E*DFF*D*2);
  unsigned short* wpb  = (unsigned short*)alloc((size_t)E*D*DFF*2);
  unsigned short* sfcb = (unsigned short*)alloc((size_t)DFF*D*2);
  unsigned short* spb  = (unsigned short*)alloc((size_t)D*DFF*2);
  unsigned short* h    = (unsigned short*)alloc((size_t)2*T*DFF*2);
  int*   tok_e   = (int*)  alloc((size_t)T*2*4);
  float* tok_w   = (float*)alloc((size_t)T*2*4);
  int*   row_tok = (int*)  alloc((size_t)2*T*4);
  float* row_w   = (float*)alloc((size_t)2*T*4);
  int* counts  = (int*)alloc(E*4);
  int* fill    = (int*)alloc(E*4);
  int* offs    = (int*)alloc((E+1)*4);
  int* nrt     = (int*)alloc(4);
  int* tile_e  = (int*)alloc(MAXRT*4);
  int* tile_r0 = (int*)alloc(MAXRT*4);
  if (off > ws_size) return;   // workspace too small -> visible zero-output failure

  hipMemsetAsync(counts, 0, E*4, stream);
  hipMemsetAsync(fill,   0, E*4, stream);

  // casts fp32 -> fp16
  cast_f16_kernel<<<(T*D/4)/256,       256, 0, stream>>>(x,     xb,   T*D/4);
  cast_f16_kernel<<<(E*DFF*D/4)/256,   256, 0, stream>>>(wfc,   wfcb, E*DFF*D/4);
  cast_f16_kernel<<<(E*D*DFF/4)/256,   256, 0, stream>>>(wproj, wpb,  E*D*DFF/4);
  cast_f16_kernel<<<(DFF*D/4)/256,     256, 0, stream>>>(sfc,   sfcb, DFF*D/4);
  cast_f16_kernel<<<(D*DFF/4)/256,     256, 0, stream>>>(sproj, spb,  D*DFF/4);

  // routing
  router_kernel <<<T/4, 256, 0, stream>>>(x, rw, tok_e, tok_w, counts);
  scan_kernel   <<<1,   64,  0, stream>>>(counts, offs, tile_e, tile_r0, nrt);
  scatter_kernel<<<(2*T)/256, 256, 0, stream>>>(tok_e, tok_w, offs, fill, row_tok, row_w);

  // shared expert (plain store initializes out)
  gemm_kernel<2><<<dim3(DFF/128, T/128), 256, 0, stream>>>(
      xb, sfcb, h, nullptr, D, DFF, nullptr, nullptr, nullptr, nullptr, nullptr, nullptr);
  gemm_kernel<3><<<dim3(D/128, T/128), 256, 0, stream>>>(
      h, spb, nullptr, out, DFF, D, nullptr, nullptr, nullptr, nullptr, nullptr, nullptr);

  // routed experts (grouped rows; atomic accumulate on top of shared)
  gemm_kernel<0><<<dim3(DFF/128, MAXRT), 256, 0, stream>>>(
      xb, wfcb, h, nullptr, D, DFF, tile_e, tile_r0, offs, nrt, row_tok, row_w);
  gemm_kernel<1><<<dim3(D/128, MAXRT), 256, 0, stream>>>(
      h, wpb, nullptr, out, DFF, D, tile_e, tile_r0, offs, nrt, row_tok, row_w);
}